// Round 1
// baseline (484.810 us; speedup 1.0000x reference)
//
#include <hip/hip_runtime.h>
#include <cstdint>
#include <cstddef>

typedef _Float16 half8 __attribute__((ext_vector_type(8)));
typedef float floatx4 __attribute__((ext_vector_type(4)));

constexpr int N = 16384;
constexpr int H = 4096;
constexpr int E = 64;
constexpr int KSPLIT = 4;
constexpr int KPW = H / KSPLIT;  // 1024 K per wave
constexpr float XSCALE = 2048.0f;   // 2^11
constexpr float WSCALE = 4096.0f;   // 2^12
constexpr float DESCALE = 1.0f / (2048.0f * 4096.0f);  // 2^-23

// ---------------- W split prekernel: W (f32) -> Whi + Wlo (f16), scaled by 2^12
__global__ __launch_bounds__(256) void wsplit_kernel(const float* __restrict__ W,
                                                     _Float16* __restrict__ Whi,
                                                     _Float16* __restrict__ Wlo) {
  int i = blockIdx.x * 256 + threadIdx.x;
  if (i >= E * H) return;
  float w = W[i] * WSCALE;
  _Float16 hi = (_Float16)w;
  _Float16 lo = (_Float16)(w - (float)hi);
  Whi[i] = hi;
  Wlo[i] = lo;
}

// split 8 f32 x-values (scaled by 2^11) into f16 hi/lo fragments
__device__ __forceinline__ void cvt_split(const float4& a, const float4& b,
                                          half8& hi, half8& lo) {
  float f[8] = {a.x, a.y, a.z, a.w, b.x, b.y, b.z, b.w};
#pragma unroll
  for (int i = 0; i < 8; ++i) {
    float s = f[i] * XSCALE;
    _Float16 h = (_Float16)s;
    _Float16 l = (_Float16)(s - (float)h);
    hi[i] = h;
    lo[i] = l;
  }
}

__device__ __forceinline__ void mfma_step(
    const float4& xa, const float4& xb,
    const half8& wh0, const half8& wh1, const half8& wh2, const half8& wh3,
    const half8& wl0, const half8& wl1, const half8& wl2, const half8& wl3,
    floatx4& acc0, floatx4& acc1, floatx4& acc2, floatx4& acc3) {
  half8 ahi, alo;
  cvt_split(xa, xb, ahi, alo);
  // small terms first, big term last (accumulation order irrelevant at this scale)
  acc0 = __builtin_amdgcn_mfma_f32_16x16x32_f16(alo, wh0, acc0, 0, 0, 0);
  acc1 = __builtin_amdgcn_mfma_f32_16x16x32_f16(alo, wh1, acc1, 0, 0, 0);
  acc2 = __builtin_amdgcn_mfma_f32_16x16x32_f16(alo, wh2, acc2, 0, 0, 0);
  acc3 = __builtin_amdgcn_mfma_f32_16x16x32_f16(alo, wh3, acc3, 0, 0, 0);
  acc0 = __builtin_amdgcn_mfma_f32_16x16x32_f16(ahi, wl0, acc0, 0, 0, 0);
  acc1 = __builtin_amdgcn_mfma_f32_16x16x32_f16(ahi, wl1, acc1, 0, 0, 0);
  acc2 = __builtin_amdgcn_mfma_f32_16x16x32_f16(ahi, wl2, acc2, 0, 0, 0);
  ac3:;
  acc3 = __builtin_amdgcn_mfma_f32_16x16x32_f16(ahi, wl3, acc3, 0, 0, 0);
  acc0 = __builtin_amdgcn_mfma_f32_16x16x32_f16(ahi, wh0, acc0, 0, 0, 0);
  acc1 = __builtin_amdgcn_mfma_f32_16x16x32_f16(ahi, wh1, acc1, 0, 0, 0);
  acc2 = __builtin_amdgcn_mfma_f32_16x16x32_f16(ahi, wh2, acc2, 0, 0, 0);
  acc3 = __builtin_amdgcn_mfma_f32_16x16x32_f16(ahi, wh3, acc3, 0, 0, 0);
}

// Main kernel: block = 256 threads = 4 waves. Block handles 16 rows, each wave
// a disjoint K-range of 1024. MFMA 16x16x32_f16, A = x rows, B = W rows (W is
// [E,H] = B-transposed layout, exactly what the b-fragment wants).
// A-frag: m = lane&15 (row), k = (lane>>4)*8 + j.  B-frag: n = lane&15 (expert).
// C/D: col = lane&15 (expert), row = (lane>>4)*4 + reg.
__global__ __launch_bounds__(256) void router_kernel(
    const float* __restrict__ x,
    const _Float16* __restrict__ Whi,
    const _Float16* __restrict__ Wlo,
    float* __restrict__ out_scores,
    float* __restrict__ out_w,
    float* __restrict__ out_i) {
  __shared__ float lds[KSPLIT][16][E];

  const int tid = threadIdx.x;
  const int wv = tid >> 6;
  const int lane = tid & 63;
  const int c = lane & 15;
  const int q = lane >> 4;
  const int r0 = blockIdx.x << 4;

  const float* xp = x + (size_t)(r0 + c) * H + (size_t)wv * KPW + q * 8;
  const _Float16* whp = Whi + (size_t)c * H + (size_t)wv * KPW + q * 8;
  const _Float16* wlp = Wlo + (size_t)c * H + (size_t)wv * KPW + q * 8;

  floatx4 acc0 = {0.f, 0.f, 0.f, 0.f};
  floatx4 acc1 = acc0, acc2 = acc0, acc3 = acc0;

  // preload chunk 0
  float4 xa = *(const float4*)(xp);
  float4 xb = *(const float4*)(xp + 4);
  half8 wh0 = *(const half8*)(whp + 0 * 16 * H);
  half8 wh1 = *(const half8*)(whp + 1 * 16 * H);
  half8 wh2 = *(const half8*)(whp + 2 * 16 * H);
  half8 wh3 = *(const half8*)(whp + 3 * 16 * H);
  half8 wl0 = *(const half8*)(wlp + 0 * 16 * H);
  half8 wl1 = *(const half8*)(wlp + 1 * 16 * H);
  half8 wl2 = *(const half8*)(wlp + 2 * 16 * H);
  half8 wl3 = *(const half8*)(wlp + 3 * 16 * H);

  for (int kc = 0; kc < KPW - 32; kc += 32) {
    const int kn = kc + 32;
    // prefetch next chunk while current computes
    float4 nxa = *(const float4*)(xp + kn);
    float4 nxb = *(const float4*)(xp + kn + 4);
    half8 nwh0 = *(const half8*)(whp + 0 * 16 * H + kn);
    half8 nwh1 = *(const half8*)(whp + 1 * 16 * H + kn);
    half8 nwh2 = *(const half8*)(whp + 2 * 16 * H + kn);
    half8 nwh3 = *(const half8*)(whp + 3 * 16 * H + kn);
    half8 nwl0 = *(const half8*)(wlp + 0 * 16 * H + kn);
    half8 nwl1 = *(const half8*)(wlp + 1 * 16 * H + kn);
    half8 nwl2 = *(const half8*)(wlp + 2 * 16 * H + kn);
    half8 nwl3 = *(const half8*)(wlp + 3 * 16 * H + kn);

    mfma_step(xa, xb, wh0, wh1, wh2, wh3, wl0, wl1, wl2, wl3,
              acc0, acc1, acc2, acc3);

    xa = nxa; xb = nxb;
    wh0 = nwh0; wh1 = nwh1; wh2 = nwh2; wh3 = nwh3;
    wl0 = nwl0; wl1 = nwl1; wl2 = nwl2; wl3 = nwl3;
  }
  mfma_step(xa, xb, wh0, wh1, wh2, wh3, wl0, wl1, wl2, wl3,
            acc0, acc1, acc2, acc3);

  // dump per-wave partials: lane holds rows q*4+r, col t*16+c
#pragma unroll
  for (int r = 0; r < 4; ++r) {
    lds[wv][q * 4 + r][0 * 16 + c] = acc0[r];
    lds[wv][q * 4 + r][1 * 16 + c] = acc1[r];
    lds[wv][q * 4 + r][2 * 16 + c] = acc2[r];
    lds[wv][q * 4 + r][3 * 16 + c] = acc3[r];
  }
  __syncthreads();

  if (wv == 0) {
    // lane = expert index (E == 64 == wave width)
    for (int row = 0; row < 16; ++row) {
      float v = (lds[0][row][lane] + lds[1][row][lane]) +
                (lds[2][row][lane] + lds[3][row][lane]);
      v *= DESCALE;
      // softmax
      float m = v;
#pragma unroll
      for (int o = 32; o > 0; o >>= 1) m = fmaxf(m, __shfl_xor(m, o));
      float ev = __expf(v - m);
      float s = ev;
#pragma unroll
      for (int o = 32; o > 0; o >>= 1) s += __shfl_xor(s, o);
      out_scores[(size_t)(r0 + row) * E + lane] = ev / s;
      // top-2 butterfly with (value desc, index asc) order — matches lax.top_k
      float v1 = v;
      int i1 = lane;
      float v2 = -3.4e38f;
      int i2 = E;
#pragma unroll
      for (int o = 32; o > 0; o >>= 1) {
        float w1 = __shfl_xor(v1, o);
        int j1 = __shfl_xor(i1, o);
        float w2 = __shfl_xor(v2, o);
        int j2 = __shfl_xor(i2, o);
        bool firstBetter = (v1 > w1) || (v1 == w1 && i1 < j1);
        float t1, t2;
        int ti1, ti2;
        if (firstBetter) {
          t1 = v1; ti1 = i1;
          bool sec = (v2 > w1) || (v2 == w1 && i2 < j1);
          t2 = sec ? v2 : w1;
          ti2 = sec ? i2 : j1;
        } else {
          t1 = w1; ti1 = j1;
          bool sec = (w2 > v1) || (w2 == v1 && j2 < i1);
          t2 = sec ? w2 : v1;
          ti2 = sec ? j2 : i1;
        }
        v1 = t1; i1 = ti1; v2 = t2; i2 = ti2;
      }
      if (lane == 0) {
        float e1 = __expf(v1 - m);
        float e2 = __expf(v2 - m);
        float inv = 1.0f / (e1 + e2);
        size_t o2 = (size_t)(r0 + row) * 2;
        out_w[o2] = e1 * inv;
        out_w[o2 + 1] = e2 * inv;
        out_i[o2] = (float)i1;
        out_i[o2 + 1] = (float)i2;
      }
    }
  }
}

extern "C" void kernel_launch(void* const* d_in, const int* in_sizes, int n_in,
                              void* d_out, int out_size, void* d_ws, size_t ws_size,
                              hipStream_t stream) {
  const float* x = (const float*)d_in[0];
  const float* W = (const float*)d_in[1];
  float* out = (float*)d_out;
  float* out_scores = out;                        // [N, 64]
  float* out_w = out + (size_t)N * E;             // [N, 2]
  float* out_i = out_w + (size_t)N * 2;           // [N, 2] (indices as floats)
  _Float16* Whi = (_Float16*)d_ws;
  _Float16* Wlo = Whi + (size_t)E * H;            // 1 MB total in ws

  wsplit_kernel<<<(E * H + 255) / 256, 256, 0, stream>>>(W, Whi, Wlo);
  router_kernel<<<N / 16, 256, 0, stream>>>(x, Whi, Wlo, out_scores, out_w, out_i);
}

// Round 2
// 397.276 us; speedup vs baseline: 1.2203x; 1.2203x over previous
//
#include <hip/hip_runtime.h>
#include <cstdint>
#include <cstddef>

typedef _Float16 half8 __attribute__((ext_vector_type(8)));
typedef float floatx4 __attribute__((ext_vector_type(4)));

constexpr int N = 16384;
constexpr int H = 4096;
constexpr int E = 64;
constexpr int BM = 32;           // rows per block
constexpr int BK = 64;           // K per stage
constexpr int NSTAGES = H / BK;  // 64
constexpr float XSCALE = 2048.0f;                      // 2^11
constexpr float WSCALE = 4096.0f;                      // 2^12
constexpr float DESCALE = 1.0f / (2048.0f * 4096.0f);  // 2^-23

// LDS byte layout (double buffered):
//   x  : [0      + buf*8192]  idx=it*256+tid -> row r=idx>>4, phys seg p=idx&15 (16B segs)
//   Whi: [16384  + buf*8192]  idx -> e=idx>>3, phys seg p=idx&7
//   Wlo: [32768  + buf*8192]
// Swizzle: phys = logical_seg ^ (row&7)  -> staging stays lane-contiguous,
// fragment ds_read_b128 is ~2-way (free) instead of 16-way conflicted.
constexpr int XBASE = 0;
constexpr int HBASE = 16384;
constexpr int LBASE = 32768;
constexpr int BUFSZ = 8192;

__device__ __forceinline__ void async16(const void* g, void* l) {
  __builtin_amdgcn_global_load_lds(
      (const __attribute__((address_space(1))) void*)g,
      (__attribute__((address_space(3))) void*)l,
      16, 0, 0);
}

// ---------------- W split prekernel: W (f32) -> Whi + Wlo (f16), scaled by 2^12
__global__ __launch_bounds__(256) void wsplit_kernel(const float* __restrict__ W,
                                                     _Float16* __restrict__ Whi,
                                                     _Float16* __restrict__ Wlo) {
  int i = blockIdx.x * 256 + threadIdx.x;
  if (i >= E * H) return;
  float w = W[i] * WSCALE;
  _Float16 hi = (_Float16)w;
  _Float16 lo = (_Float16)(w - (float)hi);
  Whi[i] = hi;
  Wlo[i] = lo;
}

// split 8 f32 x-values (scaled by 2^11) into f16 hi/lo fragments
__device__ __forceinline__ void cvt_split(const float4& a, const float4& b,
                                          half8& hi, half8& lo) {
  float f[8] = {a.x, a.y, a.z, a.w, b.x, b.y, b.z, b.w};
#pragma unroll
  for (int i = 0; i < 8; ++i) {
    float s = f[i] * XSCALE;
    _Float16 h = (_Float16)s;
    _Float16 l = (_Float16)(s - (float)h);
    hi[i] = h;
    lo[i] = l;
  }
}

__global__ __launch_bounds__(256) void router_kernel(
    const float* __restrict__ x,
    const _Float16* __restrict__ Whi,
    const _Float16* __restrict__ Wlo,
    float* __restrict__ out_scores,
    float* __restrict__ out_w,
    float* __restrict__ out_i) {
  __shared__ __align__(16) char smem[49152];

  const int tid = threadIdx.x;
  const int wv = tid >> 6;
  const int lane = tid & 63;
  const int c = lane & 15;
  const int q = lane >> 4;
  const int r0 = blockIdx.x * BM;

  // ---- staging global pointers (per thread, advance by BK elems per stage) ----
  const int xr0 = tid >> 4;                 // rows 0..15 (iter0), +16 (iter1)
  const int xp = tid & 15;                  // phys seg this thread fills
  const int xsg = xp ^ (xr0 & 7);           // logical seg to fetch (row+16: same ^)
  const float* gx0 = x + (size_t)(r0 + xr0) * H + xsg * 4;
  const float* gx1 = gx0 + (size_t)16 * H;

  const int we0 = tid >> 3;                 // experts 0..31 (iter0), +32 (iter1)
  const int wp = tid & 7;
  const int wsg = wp ^ (we0 & 7);           // (e+32)&7 == e&7
  const _Float16* gwh0 = Whi + (size_t)we0 * H + wsg * 8;
  const _Float16* gwh1 = gwh0 + (size_t)32 * H;
  const _Float16* gwl0 = Wlo + (size_t)we0 * H + wsg * 8;
  const _Float16* gwl1 = gwl0 + (size_t)32 * H;

  // ---- fragment LDS offsets (per lane) ----
  const int kh = wv >> 1;                   // K-half within stage (0/1 -> +0/+32)
  const int rblk = (wv & 1) << 4;           // row block 0 / 16
  const int xr = rblk + c;                  // my A-frag row
  const int xsegA = 2 * q + 8 * kh;         // logical 16B seg of first float4
  const int xoff0 = xr * 256 + ((xsegA ^ (xr & 7)) * 16);
  const int xoff1 = xr * 256 + (((xsegA + 1) ^ (xr & 7)) * 16);
  const int wseg = q + 4 * kh;              // logical 16B seg in f16 expert row
  const int wph = (wseg ^ (c & 7)) * 16;
  const int woff0 = (0 * 16 + c) * 128 + wph;
  const int woff1 = (1 * 16 + c) * 128 + wph;
  const int woff2 = (2 * 16 + c) * 128 + wph;
  const int woff3 = (3 * 16 + c) * 128 + wph;

  auto stage = [&](int s, int b) {
    const int kc = s * BK;   // element offset (floats for x, halves for W)
    char* xb = smem + XBASE + b * BUFSZ + tid * 16;
    async16(gx0 + kc, xb);
    async16(gx1 + kc, xb + 4096);
    char* hb = smem + HBASE + b * BUFSZ + tid * 16;
    async16(gwh0 + kc, hb);
    async16(gwh1 + kc, hb + 4096);
    char* lb = smem + LBASE + b * BUFSZ + tid * 16;
    async16(gwl0 + kc, lb);
    async16(gwl1 + kc, lb + 4096);
  };

  floatx4 acc0 = {0.f, 0.f, 0.f, 0.f};
  floatx4 acc1 = acc0, acc2 = acc0, acc3 = acc0;

  stage(0, 0);
  for (int s = 0; s < NSTAGES; ++s) {
    const int b = s & 1;
    __syncthreads();  // drains vmcnt -> buf b staged; prior compute on b done
    if (s + 1 < NSTAGES) stage(s + 1, b ^ 1);  // in flight during compute

    const char* xbb = smem + XBASE + b * BUFSZ;
    const char* hbb = smem + HBASE + b * BUFSZ;
    const char* lbb = smem + LBASE + b * BUFSZ;
    float4 xa = *(const float4*)(xbb + xoff0);
    float4 xb4 = *(const float4*)(xbb + xoff1);
    half8 h0 = *(const half8*)(hbb + woff0);
    half8 h1 = *(const half8*)(hbb + woff1);
    half8 h2 = *(const half8*)(hbb + woff2);
    half8 h3 = *(const half8*)(hbb + woff3);
    half8 l0 = *(const half8*)(lbb + woff0);
    half8 l1 = *(const half8*)(lbb + woff1);
    half8 l2 = *(const half8*)(lbb + woff2);
    half8 l3 = *(const half8*)(lbb + woff3);

    half8 ahi, alo;
    cvt_split(xa, xb4, ahi, alo);

    acc0 = __builtin_amdgcn_mfma_f32_16x16x32_f16(alo, h0, acc0, 0, 0, 0);
    acc1 = __builtin_amdgcn_mfma_f32_16x16x32_f16(alo, h1, acc1, 0, 0, 0);
    acc2 = __builtin_amdgcn_mfma_f32_16x16x32_f16(alo, h2, acc2, 0, 0, 0);
    acc3 = __builtin_amdgcn_mfma_f32_16x16x32_f16(alo, h3, acc3, 0, 0, 0);
    acc0 = __builtin_amdgcn_mfma_f32_16x16x32_f16(ahi, l0, acc0, 0, 0, 0);
    acc1 = __builtin_amdgcn_mfma_f32_16x16x32_f16(ahi, l1, acc1, 0, 0, 0);
    acc2 = __builtin_amdgcn_mfma_f32_16x16x32_f16(ahi, l2, acc2, 0, 0, 0);
    acc3 = __builtin_amdgcn_mfma_f32_16x16x32_f16(ahi, l3, acc3, 0, 0, 0);
    acc0 = __builtin_amdgcn_mfma_f32_16x16x32_f16(ahi, h0, acc0, 0, 0, 0);
    acc1 = __builtin_amdgcn_mfma_f32_16x16x32_f16(ahi, h1, acc1, 0, 0, 0);
    acc2 = __builtin_amdgcn_mfma_f32_16x16x32_f16(ahi, h2, acc2, 0, 0, 0);
    acc3 = __builtin_amdgcn_mfma_f32_16x16x32_f16(ahi, h3, acc3, 0, 0, 0);
  }

  // ---- reduce K-halves via LDS, then per-row softmax/top2 ----
  __syncthreads();  // everyone done reading x bufs (red aliases them)
  float* red = (float*)smem;  // [2 kh][32 rows][64 e] = 16 KB
#pragma unroll
  for (int r = 0; r < 4; ++r) {
    const int row = rblk + q * 4 + r;
    float* rp = red + (kh * 32 + row) * 64;
    rp[0 * 16 + c] = acc0[r];
    rp[1 * 16 + c] = acc1[r];
    rp[2 * 16 + c] = acc2[r];
    rp[3 * 16 + c] = acc3[r];
  }
  __syncthreads();

  // 4 waves x 8 rows each; lane = expert (E == 64 == wave width)
  for (int row = wv * 8; row < wv * 8 + 8; ++row) {
    float v = red[row * 64 + lane] + red[(32 + row) * 64 + lane];
    v *= DESCALE;
    // softmax
    float m = v;
#pragma unroll
    for (int o = 32; o > 0; o >>= 1) m = fmaxf(m, __shfl_xor(m, o));
    float ev = __expf(v - m);
    float ssum = ev;
#pragma unroll
    for (int o = 32; o > 0; o >>= 1) ssum += __shfl_xor(ssum, o);
    out_scores[(size_t)(r0 + row) * E + lane] = ev / ssum;
    // top-2 butterfly with (value desc, index asc) order — matches lax.top_k
    float v1 = v;
    int i1 = lane;
    float v2 = -3.4e38f;
    int i2 = E;
#pragma unroll
    for (int o = 32; o > 0; o >>= 1) {
      float w1 = __shfl_xor(v1, o);
      int j1 = __shfl_xor(i1, o);
      float w2 = __shfl_xor(v2, o);
      int j2 = __shfl_xor(i2, o);
      bool firstBetter = (v1 > w1) || (v1 == w1 && i1 < j1);
      float t1, t2;
      int ti1, ti2;
      if (firstBetter) {
        t1 = v1; ti1 = i1;
        bool sec = (v2 > w1) || (v2 == w1 && i2 < j1);
        t2 = sec ? v2 : w1;
        ti2 = sec ? i2 : j1;
      } else {
        t1 = w1; ti1 = j1;
        bool sec = (w2 > v1) || (w2 == v1 && j2 < i1);
        t2 = sec ? w2 : v1;
        ti2 = sec ? j2 : i1;
      }
      v1 = t1; i1 = ti1; v2 = t2; i2 = ti2;
    }
    if (lane == 0) {
      float e1 = __expf(v1 - m);
      float e2 = __expf(v2 - m);
      float inv = 1.0f / (e1 + e2);
      size_t o2 = (size_t)(r0 + row) * 2;
      out_w[o2] = e1 * inv;
      out_w[o2 + 1] = e2 * inv;
      out_i[o2] = (float)i1;
      out_i[o2 + 1] = (float)i2;
    }
  }
}

extern "C" void kernel_launch(void* const* d_in, const int* in_sizes, int n_in,
                              void* d_out, int out_size, void* d_ws, size_t ws_size,
                              hipStream_t stream) {
  const float* x = (const float*)d_in[0];
  const float* W = (const float*)d_in[1];
  float* out = (float*)d_out;
  float* out_scores = out;                  // [N, 64]
  float* out_w = out + (size_t)N * E;       // [N, 2]
  float* out_i = out_w + (size_t)N * 2;     // [N, 2] (indices as floats)
  _Float16* Whi = (_Float16*)d_ws;
  _Float16* Wlo = Whi + (size_t)E * H;      // 1 MB total in ws

  wsplit_kernel<<<(E * H + 255) / 256, 256, 0, stream>>>(W, Whi, Wlo);
  router_kernel<<<N / BM, 256, 0, stream>>>(x, Whi, Wlo, out_scores, out_w, out_i);
}